// Round 5
// baseline (156.696 us; speedup 1.0000x reference)
//
#include <hip/hip_runtime.h>

#define N_PTS   4096
#define N_BATCH 16
#define BLOCK   256
#define NB      4                  // B fragments (16 queries each) per wave
#define INV_CNT (1.0f / (2.0f * N_BATCH * N_PTS))

typedef _Float16 f16x8 __attribute__((ext_vector_type(8)));
typedef float    f32x4 __attribute__((ext_vector_type(4)));

// ws layout (halves): arow[2 sets][16 batches][4096 pts][16 halves] = 4 MB.
// A-row K-slots for opposite point o (split o = oh + ol in f16):
//   [0..7]  = -2oh_x,-2oh_y,-2oh_z, -2oh_x,-2oh_y,-2oh_z, -2ol_x,-2ol_y
//   [8..15] = -2ol_z, o2h, o2l, 0,0,0,0,0        (o2 = |o|^2, f16 hi/lo split)
// Paired B-row slots (query p = ph + pl):
//   [0..7]  = ph_x,ph_y,ph_z, pl_x,pl_y,pl_z, ph_x,ph_y
//   [8..15] = ph_z, 1, 1, 0,0,0,0,0
// => one 16x16x32 f16 MFMA accumulates C = o2 - 2*(o.p) in f32
//    (error ~ dropped ol*pl + f16 split residue ~ 5e-6 absolute).
__global__ __launch_bounds__(BLOCK) void prep_kernel(
    const float* __restrict__ tpl, const float* __restrict__ src,
    _Float16* __restrict__ arow, float* __restrict__ out) {
    int pt = blockIdx.x * BLOCK + threadIdx.x;        // 0..131071 (T then S)
    if (pt == 0) out[0] = 0.0f;                       // main runs after (stream order)
    const float* p = (pt < 65536 ? tpl : src) + (size_t)(pt & 65535) * 3;
    float x = p[0], y = p[1], z = p[2];
    float o2 = fmaf(x, x, fmaf(y, y, z * z));
    _Float16 xh = (_Float16)x, yh = (_Float16)y, zh = (_Float16)z;
    _Float16 xl = (_Float16)(x - (float)xh);
    _Float16 yl = (_Float16)(y - (float)yh);
    _Float16 zl = (_Float16)(z - (float)zh);
    _Float16 o2h = (_Float16)o2;
    _Float16 o2l = (_Float16)(o2 - (float)o2h);
    const _Float16 m2 = (_Float16)-2.0f;              // exact scaling in f16
    f16x8 v0, v1;
    v0[0] = m2 * xh; v0[1] = m2 * yh; v0[2] = m2 * zh;
    v0[3] = m2 * xh; v0[4] = m2 * yh; v0[5] = m2 * zh;
    v0[6] = m2 * xl; v0[7] = m2 * yl;
    v1[0] = m2 * zl; v1[1] = o2h; v1[2] = o2l;
    v1[3] = (_Float16)0.0f; v1[4] = (_Float16)0.0f; v1[5] = (_Float16)0.0f;
    v1[6] = (_Float16)0.0f; v1[7] = (_Float16)0.0f;
    *(f16x8*)(arow + (size_t)pt * 16)     = v0;
    *(f16x8*)(arow + (size_t)pt * 16 + 8) = v1;
}

// Grid (16 qblocks, 16 batches, 2 dirs). Block = 4 waves; wave owns 64 queries
// (NB=4 B-frags). Iterates all 4096 opposite points in 16 chunks of 256
// (16 MFMA tiles each), double-buffered through LDS.
// C layout: col = lane&15 (query n), row = (lane>>4)*4 + reg (opposite) — min
// over rows = in-lane fmin + cross-group shfl_xor(16/32) at the end.
__global__ __launch_bounds__(BLOCK, 2) void chamfer_mfma(
    const float* __restrict__ tpl, const float* __restrict__ src,
    const _Float16* __restrict__ arow, float* __restrict__ out) {
    __shared__ float4 smem[2][512];   // 2 x 8KB staging (256 opposite pts/chunk)
    __shared__ float wsum[4];

    const int tid = threadIdx.x;
    const int wv = tid >> 6, lane = tid & 63;
    const int g = lane >> 4, n = lane & 15;
    const int qb = blockIdx.x, batch = blockIdx.y, dir = blockIdx.z;

    const float* qpts = (dir == 0) ? src : tpl;       // dist1: query = source
    const _Float16* ab = arow + ((dir == 0) ? (size_t)0 : (size_t)65536 * 16)
                       + (size_t)batch * 4096 * 16;   // opposite set A-rows
    const int qbase = qb * 256 + wv * 64;

    // Build B fragments + |p|^2 in registers (lane n -> query qbase+16i+n).
    f16x8 bf[NB];
    float p2[NB], acc[NB];
    #pragma unroll
    for (int i = 0; i < NB; ++i) {
        int q = qbase + i * 16 + n;
        const float* p = qpts + (size_t)(batch * 4096 + q) * 3;
        float x = p[0], y = p[1], z = p[2];
        p2[i] = fmaf(x, x, fmaf(y, y, z * z));
        _Float16 xh = (_Float16)x, yh = (_Float16)y, zh = (_Float16)z;
        _Float16 xl = (_Float16)(x - (float)xh);
        _Float16 yl = (_Float16)(y - (float)yh);
        _Float16 zl = (_Float16)(z - (float)zh);
        f16x8 b;
        #pragma unroll
        for (int j = 0; j < 8; ++j) b[j] = (_Float16)0.0f;
        if (g == 0) {
            b[0] = xh; b[1] = yh; b[2] = zh;
            b[3] = xl; b[4] = yl; b[5] = zl;
            b[6] = xh; b[7] = yh;
        } else if (g == 1) {
            b[0] = zh; b[1] = (_Float16)1.0f; b[2] = (_Float16)1.0f;
        }
        bf[i] = b;
        acc[i] = 1e30f;
    }

    // Prime chunk 0.
    const float4* gsrc = (const float4*)ab;           // 8192 float4 = 4096 pts
    float4 r0 = gsrc[tid * 2], r1 = gsrc[tid * 2 + 1];
    smem[0][tid * 2] = r0; smem[0][tid * 2 + 1] = r1;
    __syncthreads();

    #pragma unroll 1
    for (int c = 0; c < 16; ++c) {
        const int buf = c & 1;
        if (c < 15) {                                  // prefetch next chunk
            r0 = gsrc[(c + 1) * 512 + tid * 2];
            r1 = gsrc[(c + 1) * 512 + tid * 2 + 1];
        }
        const char* base = (const char*)&smem[buf][0];
        #pragma unroll
        for (int t8 = 0; t8 < 16; ++t8) {
            f16x8 a;
            #pragma unroll
            for (int j = 0; j < 8; ++j) a[j] = (_Float16)0.0f;
            if (g < 2)                                 // groups 2,3: K>=16 all zero
                a = *(const f16x8*)(base + t8 * 512 + n * 32 + g * 16);
            #pragma unroll
            for (int i = 0; i < NB; ++i) {
                f32x4 cz = {0.0f, 0.0f, 0.0f, 0.0f};
                f32x4 d4 = __builtin_amdgcn_mfma_f32_16x16x32_f16(a, bf[i], cz, 0, 0, 0);
                acc[i] = fminf(acc[i],
                               fminf(fminf(d4[0], d4[1]), fminf(d4[2], d4[3])));
            }
        }
        if (c < 15) {
            // buf^1 was fully consumed before the barrier at end of c-1: safe.
            smem[buf ^ 1][tid * 2] = r0; smem[buf ^ 1][tid * 2 + 1] = r1;
            __syncthreads();
        }
    }

    // Cross-group min (rows split across lane groups), then epilogue.
    float s = 0.0f;
    #pragma unroll
    for (int i = 0; i < NB; ++i) {
        float v = acc[i];
        v = fminf(v, __shfl_xor(v, 16));
        v = fminf(v, __shfl_xor(v, 32));
        float d = fmaxf(v + p2[i], 0.0f);              // == min of clamped (monotone)
        s += sqrtf(d);
    }
    s *= INV_CNT;
    if (g != 0) s = 0.0f;                              // count each query once
    #pragma unroll
    for (int off = 32; off > 0; off >>= 1) s += __shfl_down(s, off);
    if (lane == 0) wsum[wv] = s;
    __syncthreads();
    if (tid == 0) atomicAdd(out, wsum[0] + wsum[1] + wsum[2] + wsum[3]);
}

extern "C" void kernel_launch(void* const* d_in, const int* in_sizes, int n_in,
                              void* d_out, int out_size, void* d_ws, size_t ws_size,
                              hipStream_t stream) {
    const float* tpl = (const float*)d_in[0];
    const float* src = (const float*)d_in[1];
    float* out = (float*)d_out;
    _Float16* arow = (_Float16*)d_ws;                  // 4 MB

    hipLaunchKernelGGL(prep_kernel, dim3((2 * N_BATCH * N_PTS) / BLOCK),
                       dim3(BLOCK), 0, stream, tpl, src, arow, out);
    dim3 grid(N_PTS / 256, N_BATCH, 2);                // (16, 16, 2) = 512 blocks
    hipLaunchKernelGGL(chamfer_mfma, grid, dim3(BLOCK), 0, stream,
                       tpl, src, arow, out);
}

// Round 6
// 114.657 us; speedup vs baseline: 1.3666x; 1.3666x over previous
//
#include <hip/hip_runtime.h>

#define N_PTS   4096
#define N_BATCH 16
#define BLOCK   256
#define NB      2                  // B fragments (32 queries each) per wave
#define INV_CNT (1.0f / (2.0f * N_BATCH * N_PTS))

typedef _Float16 f16x8  __attribute__((ext_vector_type(8)));
typedef float    f32x16 __attribute__((ext_vector_type(16)));

// 32x32x16 f16 MFMA, K-slot packing (split o = oh + ol, p = ph + pl in f16):
//   A-row (opposite point o), 16 halves (32 B):
//     [0..7]  = -2oh_x,-2oh_y,-2oh_z, -2ol_x,-2ol_y,-2ol_z, -2oh_x,-2oh_y
//     [8..15] = -2oh_z, o2h, o2l, 0,0,0,0,0         (o2 = |o|^2 hi/lo split)
//   B-col (query p):
//     [0..7]  = ph_x,ph_y,ph_z, ph_x,ph_y,ph_z, pl_x,pl_y
//     [8..15] = pl_z, 1, 1, 0,0,0,0,0
//   => C = o2 - 2 o.p  (dropped ol.pl ~ 2^-22 -- negligible; R5 passed same math)
// Lane layouts (32x32x16): A: row=l&31, k=(l>>5)*8+j. B: col=l&31, same k.
// C: col=l&31, row covers all 32 via 16 regs + lane>>5 -> min = reg-min + shfl_xor(32).
__global__ __launch_bounds__(BLOCK) void prep_kernel(
    const float* __restrict__ tpl, const float* __restrict__ src,
    _Float16* __restrict__ arow, float* __restrict__ out) {
    int pt = blockIdx.x * BLOCK + threadIdx.x;        // 0..131071 (T set, then S set)
    if (pt == 0) out[0] = 0.0f;                       // main runs after (stream order)
    const float* p = (pt < 65536 ? tpl : src) + (size_t)(pt & 65535) * 3;
    float x = p[0], y = p[1], z = p[2];
    float o2 = fmaf(x, x, fmaf(y, y, z * z));
    _Float16 xh = (_Float16)x, yh = (_Float16)y, zh = (_Float16)z;
    _Float16 xl = (_Float16)(x - (float)xh);
    _Float16 yl = (_Float16)(y - (float)yh);
    _Float16 zl = (_Float16)(z - (float)zh);
    _Float16 o2h = (_Float16)o2;
    _Float16 o2l = (_Float16)(o2 - (float)o2h);
    const _Float16 m2 = (_Float16)-2.0f;              // exact power-of-2 scale
    f16x8 v0, v1;
    v0[0] = m2 * xh; v0[1] = m2 * yh; v0[2] = m2 * zh;
    v0[3] = m2 * xl; v0[4] = m2 * yl; v0[5] = m2 * zl;
    v0[6] = m2 * xh; v0[7] = m2 * yh;
    v1[0] = m2 * zh; v1[1] = o2h; v1[2] = o2l;
    v1[3] = (_Float16)0.0f; v1[4] = (_Float16)0.0f; v1[5] = (_Float16)0.0f;
    v1[6] = (_Float16)0.0f; v1[7] = (_Float16)0.0f;
    *(f16x8*)(arow + (size_t)pt * 16)     = v0;
    *(f16x8*)(arow + (size_t)pt * 16 + 8) = v1;
}

// Grid (16 qblocks, 16 batches, 2 dirs) = 512 blocks x 4 waves.
// Wave owns 64 queries (NB=2 frags of 32); iterates 128 A-tiles (32 pts each)
// loaded DIRECTLY global->register (16 B/lane, wave reads 1 contiguous KB).
// The block's 4 waves share the same A-stream -> L1 serves 3/4 of rereads.
__global__ __launch_bounds__(BLOCK, 2) void chamfer_mfma(
    const float* __restrict__ tpl, const float* __restrict__ src,
    const _Float16* __restrict__ arow, float* __restrict__ out) {
    __shared__ float wsum[4];

    const int tid = threadIdx.x;
    const int wv = tid >> 6, lane = tid & 63;
    const int n = lane & 31, g = lane >> 5;           // B col / K-half group
    const int qb = blockIdx.x, batch = blockIdx.y, dir = blockIdx.z;

    const float* qpts = (dir == 0) ? src : tpl;       // dist1: query = source
    const _Float16* abase = arow + ((dir == 0) ? (size_t)0 : (size_t)65536 * 16)
                          + (size_t)batch * 4096 * 16;

    // Build B fragments + |p|^2 (lane n -> query qbase + i*32 + n).
    f16x8 bf[NB];
    float p2[NB], acc[NB];
    #pragma unroll
    for (int i = 0; i < NB; ++i) {
        int q = qb * 256 + wv * 64 + i * 32 + n;
        const float* p = qpts + (size_t)(batch * 4096 + q) * 3;
        float x = p[0], y = p[1], z = p[2];
        p2[i] = fmaf(x, x, fmaf(y, y, z * z));
        _Float16 xh = (_Float16)x, yh = (_Float16)y, zh = (_Float16)z;
        _Float16 xl = (_Float16)(x - (float)xh);
        _Float16 yl = (_Float16)(y - (float)yh);
        _Float16 zl = (_Float16)(z - (float)zh);
        f16x8 b;
        if (g == 0) {
            b[0] = xh; b[1] = yh; b[2] = zh;
            b[3] = xh; b[4] = yh; b[5] = zh;
            b[6] = xl; b[7] = yl;
        } else {
            b[0] = zl; b[1] = (_Float16)1.0f; b[2] = (_Float16)1.0f;
            b[3] = (_Float16)0.0f; b[4] = (_Float16)0.0f; b[5] = (_Float16)0.0f;
            b[6] = (_Float16)0.0f; b[7] = (_Float16)0.0f;
        }
        bf[i] = b;
        acc[i] = 1e30f;
    }

    // Lane's A-fragment stream: tile t -> abase + t*1024B + (l&31)*32B + (l>>5)*16B.
    const f16x8* ap = (const f16x8*)abase + (size_t)n * 2 + g;
    const f32x16 cz = {0.0f, 0.0f, 0.0f, 0.0f, 0.0f, 0.0f, 0.0f, 0.0f,
                       0.0f, 0.0f, 0.0f, 0.0f, 0.0f, 0.0f, 0.0f, 0.0f};

    f16x8 a = ap[0];
    #pragma unroll 1
    for (int t = 0; t < 128; ++t) {
        f16x8 an = ap[(size_t)((t + 1) & 127) * 64];   // prefetch (wraps: harmless)
        f32x16 c0 = __builtin_amdgcn_mfma_f32_32x32x16_f16(a, bf[0], cz, 0, 0, 0);
        f32x16 c1 = __builtin_amdgcn_mfma_f32_32x32x16_f16(a, bf[1], cz, 0, 0, 0);
        #pragma unroll
        for (int r = 0; r < 16; r += 2) {
            acc[0] = fminf(acc[0], fminf(c0[r], c0[r + 1]));  // -> v_min3_f32
            acc[1] = fminf(acc[1], fminf(c1[r], c1[r + 1]));
        }
        a = an;
    }

    // Rows split across the two lane halves; fold, then epilogue.
    float s = 0.0f;
    #pragma unroll
    for (int i = 0; i < NB; ++i) {
        float v = acc[i];
        v = fminf(v, __shfl_xor(v, 32));
        float d = fmaxf(v + p2[i], 0.0f);              // == min of clamped (monotone)
        s += sqrtf(d);
    }
    s *= INV_CNT;
    if (g != 0) s = 0.0f;                              // count each query once
    #pragma unroll
    for (int off = 32; off > 0; off >>= 1) s += __shfl_down(s, off);
    if (lane == 0) wsum[wv] = s;
    __syncthreads();
    if (tid == 0) atomicAdd(out, wsum[0] + wsum[1] + wsum[2] + wsum[3]);
}

extern "C" void kernel_launch(void* const* d_in, const int* in_sizes, int n_in,
                              void* d_out, int out_size, void* d_ws, size_t ws_size,
                              hipStream_t stream) {
    const float* tpl = (const float*)d_in[0];
    const float* src = (const float*)d_in[1];
    float* out = (float*)d_out;
    _Float16* arow = (_Float16*)d_ws;                  // 131072 pts x 32 B = 4 MB

    hipLaunchKernelGGL(prep_kernel, dim3((2 * N_BATCH * N_PTS) / BLOCK),
                       dim3(BLOCK), 0, stream, tpl, src, arow, out);
    dim3 grid(N_PTS / 256, N_BATCH, 2);                // (16, 16, 2) = 512 blocks
    hipLaunchKernelGGL(chamfer_mfma, grid, dim3(BLOCK), 0, stream,
                       tpl, src, arow, out);
}